// Round 5
// baseline (392.833 us; speedup 1.0000x reference)
//
#include <hip/hip_runtime.h>
#include <math.h>

// Problem constants (match reference)
#define B_TOK 16384
#define H_DIM 2048
#define NE    8
#define TOPK  2
#define HFD   512

// Expert-kernel tiling
#define TM 128    // tokens per block tile
#define BK 32     // K chunk per pipeline stage
#define NKSTEP (H_DIM / BK)   // 64
#define NSTAGE 3  // pipeline depth

// Workspace layout (bytes)
static constexpr size_t OFF_COUNTS = 0;                                     // 32 B
static constexpr size_t OFF_BUCKET = 1024;                                  // 512 KB
static constexpr size_t OFF_WSLOT  = OFF_BUCKET + (size_t)NE * B_TOK * 4;   // 525312
static constexpr size_t OFF_ROUTE  = OFF_WSLOT + (size_t)B_TOK * 2 * 4;     // 656384
static constexpr size_t OFF_WGT    = 720896;                                // 64 KB
static constexpr size_t OFF_W1TS   = 1u << 20;                              // 16 MB
static constexpr size_t OFF_XB     = OFF_W1TS + (size_t)NE * HFD * H_DIM * 2; // 17 MB
// xb = 64 MB -> total ws use ~81 MB

typedef short bfrag __attribute__((ext_vector_type(8)));   // 8 bf16 (4 VGPR)
typedef float facc  __attribute__((ext_vector_type(16)));  // 32x32 accum

// fp32 -> bf16 (round-to-nearest-even)
__device__ inline unsigned short f2bf(float f) {
    union { float f; unsigned u; } v; v.f = f;
    unsigned r = v.u + 0x7FFFu + ((v.u >> 16) & 1u);
    return (unsigned short)(r >> 16);
}
__device__ inline unsigned pack2(float lo, float hi) {
    return (unsigned)f2bf(lo) | ((unsigned)f2bf(hi) << 16);
}

__device__ __forceinline__ void gload_lds16(const void* g, void* l) {
    __builtin_amdgcn_global_load_lds(
        (const __attribute__((address_space(1))) unsigned int*)g,
        (__attribute__((address_space(3))) unsigned int*)l, 16, 0, 0);
}

// ---------------------------------------------------------------------------
// Transpose gate weights: Wg [H][E] -> WgT [E][H].
// ---------------------------------------------------------------------------
__global__ __launch_bounds__(256)
void wg_transpose_kernel(const float* __restrict__ Wg,
                         float* __restrict__ WgT)
{
    const int t = threadIdx.x;
    #pragma unroll
    for (int rep = 0; rep < H_DIM / 256; ++rep) {
        const int h = rep * 256 + t;
        const float4 a = *reinterpret_cast<const float4*>(Wg + (size_t)h * NE);
        const float4 b = *reinterpret_cast<const float4*>(Wg + (size_t)h * NE + 4);
        WgT[0 * H_DIM + h] = a.x;  WgT[1 * H_DIM + h] = a.y;
        WgT[2 * H_DIM + h] = a.z;  WgT[3 * H_DIM + h] = a.w;
        WgT[4 * H_DIM + h] = b.x;  WgT[5 * H_DIM + h] = b.y;
        WgT[6 * H_DIM + h] = b.z;  WgT[7 * H_DIM + h] = b.w;
    }
}

// ---------------------------------------------------------------------------
// Prep W1: [E][H][HF] fp32 -> k-slot-major bf16 image:
//   W1ts[e][kstep][slot(0..3)][f(0..511)][j(0..7)]  (element k = kstep*32+slot*8+j)
// Each (e,kstep) block of 16384 elems (32 KB) is exactly one LDS A-stage image.
// ---------------------------------------------------------------------------
__global__ __launch_bounds__(256)
void prep_w1_kernel(const float* __restrict__ W1,
                    unsigned short* __restrict__ W1ts)
{
    const int blk   = blockIdx.x;       // e*64 + kstep
    const int e     = blk >> 6;
    const int kstep = blk & 63;
    const int tid   = threadIdx.x;

    const float* src = W1 + ((size_t)e * H_DIM + kstep * BK) * HFD;
    unsigned short* dst = W1ts + (size_t)e * (HFD * H_DIM) + (size_t)kstep * (BK * HFD);

    #pragma unroll
    for (int s = 0; s < 4; ++s) {
        #pragma unroll
        for (int fh = 0; fh < 2; ++fh) {
            const int f = fh * 256 + tid;
            float v[8];
            #pragma unroll
            for (int j = 0; j < 8; ++j)
                v[j] = src[(size_t)(s * 8 + j) * HFD + f];   // coalesced across lanes
            uint4 p;
            p.x = pack2(v[0], v[1]); p.y = pack2(v[2], v[3]);
            p.z = pack2(v[4], v[5]); p.w = pack2(v[6], v[7]);
            *reinterpret_cast<uint4*>(dst + s * 4096 + f * 8) = p;
        }
    }
}

// ---------------------------------------------------------------------------
// Gate logits + x->bf16 conversion (atomic-free). One wave per token.
// ---------------------------------------------------------------------------
__global__ __launch_bounds__(256)
void gate_logits_kernel(const float* __restrict__ x,
                        const float* __restrict__ WgT,
                        const float* __restrict__ bg,
                        float* __restrict__ out_logits,
                        float* __restrict__ wslot,
                        int*   __restrict__ route,
                        unsigned short* __restrict__ xb)
{
    const int tok  = (blockIdx.x * blockDim.x + threadIdx.x) >> 6;
    const int lane = threadIdx.x & 63;
    if (tok >= B_TOK) return;

    const float* xrow = x + (size_t)tok * H_DIM;
    unsigned short* xbrow = xb + (size_t)tok * H_DIM;

    float acc[NE];
    #pragma unroll
    for (int e = 0; e < NE; ++e) acc[e] = 0.f;

    #pragma unroll 2
    for (int i = 0; i < H_DIM / 256; ++i) {
        const int h = i * 256 + 4 * lane;
        const float4 xv = *reinterpret_cast<const float4*>(xrow + h);
        uint2 p;
        p.x = pack2(xv.x, xv.y);
        p.y = pack2(xv.z, xv.w);
        *reinterpret_cast<uint2*>(xbrow + h) = p;
        #pragma unroll
        for (int e = 0; e < NE; ++e) {
            const float4 wv = *reinterpret_cast<const float4*>(WgT + (size_t)e * H_DIM + h);
            acc[e] += xv.x * wv.x + xv.y * wv.y + xv.z * wv.z + xv.w * wv.w;
        }
    }

    #pragma unroll
    for (int e = 0; e < NE; ++e) {
        #pragma unroll
        for (int off = 32; off > 0; off >>= 1)
            acc[e] += __shfl_xor(acc[e], off, 64);
    }

    if (lane == 0) {
        #pragma unroll
        for (int e = 0; e < NE; ++e) acc[e] += bg[e];

        float4* lo = reinterpret_cast<float4*>(out_logits + (size_t)tok * NE);
        lo[0] = make_float4(acc[0], acc[1], acc[2], acc[3]);
        lo[1] = make_float4(acc[4], acc[5], acc[6], acc[7]);

        int i0 = 0; float v0 = acc[0];
        #pragma unroll
        for (int e = 1; e < NE; ++e)
            if (acc[e] > v0) { v0 = acc[e]; i0 = e; }
        int i1 = -1; float v1 = -3.4e38f;
        #pragma unroll
        for (int e = 0; e < NE; ++e)
            if (e != i0 && acc[e] > v1) { v1 = acc[e]; i1 = e; }

        const float w0 = 1.f / (1.f + expf(v1 - v0));
        wslot[tok * 2]     = w0;
        wslot[tok * 2 + 1] = 1.f - w0;
        route[tok] = i0 | (i1 << 8);
    }
}

// ---------------------------------------------------------------------------
// Route/bucket: LDS-aggregated histogram; 8 global atomics per block.
// ---------------------------------------------------------------------------
__global__ __launch_bounds__(1024)
void route_kernel(const int* __restrict__ route,
                  int* __restrict__ counts,
                  int* __restrict__ bucket)
{
    __shared__ int lcnt[NE];
    __shared__ int lbase[NE];
    const int tid = threadIdx.x;
    const int tok = blockIdx.x * 1024 + tid;

    if (tid < NE) lcnt[tid] = 0;
    __syncthreads();

    const int rt = route[tok];
    const int i0 = rt & 255;
    const int i1 = rt >> 8;
    const int r0 = atomicAdd(&lcnt[i0], 1);
    const int r1 = atomicAdd(&lcnt[i1], 1);
    __syncthreads();

    if (tid < NE) lbase[tid] = atomicAdd(&counts[tid], lcnt[tid]);
    __syncthreads();

    bucket[i0 * B_TOK + lbase[i0] + r0] = tok * 2;
    bucket[i1 * B_TOK + lbase[i1] + r1] = tok * 2 + 1;
}

// ---------------------------------------------------------------------------
// Expert MFMA kernel: 512 thr / 8 waves; wave w = (tg = w>>2)*4 + (fr = w&3):
// owns f rows [fr*128, fr*128+128) x tokens [tg*64, tg*64+64) -> 4x2 frags.
// Depth-3 pipeline: per step each wave issues exactly 5 global_load_lds
// (4 A-chunks + 1 X-chunk); vmcnt(10) keeps 2 steps in flight (never 0 in
// the loop). Expert pinned to XCD via e = blockIdx & 7.
// ---------------------------------------------------------------------------
__global__ __launch_bounds__(512, 2)
void expert_mfma_kernel(const unsigned short* __restrict__ xb,
                        const unsigned short* __restrict__ W1ts,
                        const float* __restrict__ b1,
                        const float* __restrict__ W2,
                        const int*   __restrict__ counts,
                        const int*   __restrict__ bucket,
                        const float* __restrict__ wslot,
                        float* __restrict__ out_scores)
{
    const int e = blockIdx.x & 7;
    const int t = blockIdx.x >> 3;
    const int n = counts[e];
    const int start = t * TM;
    if (start >= n) return;
    const int nt = min(TM, n - start);

    __shared__ unsigned short Abuf[NSTAGE][4 * HFD * 8];   // 32 KB per stage
    __shared__ unsigned short Xbuf[NSTAGE][4 * TM * 8];    // 8 KB per stage
    __shared__ float o_part[4][TM];

    const int tid = threadIdx.x;
    const int w   = tid >> 6;
    const int l   = tid & 63;
    const int lo5 = l & 31;
    const int hi  = l >> 5;
    const int fr  = w & 3;       // f-group (128 rows)
    const int tg  = w >> 2;      // token group (64 cols)

    const unsigned short* W1e = W1ts + (size_t)e * (HFD * H_DIM);

    // X staging role: wave w stages k-slot (w&3) for token-half (w>>2).
    const int sx   = w & 3;
    const int th   = w >> 2;
    const int xtok = th * 64 + l;
    const int xent = bucket[e * B_TOK + start + min(xtok, nt - 1)];
    const unsigned short* xsrc = xb + (size_t)(xent >> 1) * H_DIM + sx * 8;
    unsigned short* xdst_base[NSTAGE];
    #pragma unroll
    for (int s = 0; s < NSTAGE; ++s)
        xdst_base[s] = &Xbuf[s][(sx * TM + xtok) * 8];

    facc acc[4][2];
    #pragma unroll
    for (int m = 0; m < 4; ++m)
        #pragma unroll
        for (int nb = 0; nb < 2; ++nb)
            #pragma unroll
            for (int r = 0; r < 16; ++r) acc[m][nb][r] = 0.f;

    // ---- stage helper: 4 A-chunks + 1 X-chunk per wave (exactly 5 loads) --
    #define STAGE(KK, BUF) do {                                               \
        const unsigned short* asrc_ = W1e + (size_t)(KK) * (BK * HFD);        \
        const int c0_ = w * 4;                                                \
        gload_lds16(asrc_ + (c0_ + 0) * 512 + l * 8, &Abuf[BUF][(c0_ + 0) * 512 + l * 8]); \
        gload_lds16(asrc_ + (c0_ + 1) * 512 + l * 8, &Abuf[BUF][(c0_ + 1) * 512 + l * 8]); \
        gload_lds16(asrc_ + (c0_ + 2) * 512 + l * 8, &Abuf[BUF][(c0_ + 2) * 512 + l * 8]); \
        gload_lds16(asrc_ + (c0_ + 3) * 512 + l * 8, &Abuf[BUF][(c0_ + 3) * 512 + l * 8]); \
        gload_lds16(xsrc + (size_t)(KK) * BK, xdst_base[BUF]);                \
    } while (0)

    STAGE(0, 0);
    STAGE(1, 1);

    int cur = 0;
    for (int kk = 0; kk < NKSTEP; ++kk) {
        if (kk + 2 < NKSTEP) {
            const int sb = (cur + 2 >= NSTAGE) ? (cur + 2 - NSTAGE) : (cur + 2);
            STAGE(kk + 2, sb);
            asm volatile("s_waitcnt vmcnt(10)" ::: "memory");   // step kk done
        } else if (kk + 1 < NKSTEP) {
            asm volatile("s_waitcnt vmcnt(5)" ::: "memory");
        } else {
            asm volatile("s_waitcnt vmcnt(0)" ::: "memory");
        }
        __builtin_amdgcn_s_barrier();   // buf[cur] visible to all waves

        __builtin_amdgcn_s_setprio(1);
        #pragma unroll
        for (int ks = 0; ks < 2; ++ks) {
            const int slot = ks * 2 + hi;
            bfrag a[4], bb[2];
            #pragma unroll
            for (int m = 0; m < 4; ++m)
                a[m] = *reinterpret_cast<const bfrag*>(
                    &Abuf[cur][(slot * 512 + fr * 128 + m * 32 + lo5) * 8]);
            #pragma unroll
            for (int nb = 0; nb < 2; ++nb)
                bb[nb] = *reinterpret_cast<const bfrag*>(
                    &Xbuf[cur][(slot * TM + tg * 64 + nb * 32 + lo5) * 8]);
            #pragma unroll
            for (int m = 0; m < 4; ++m)
                #pragma unroll
                for (int nb = 0; nb < 2; ++nb)
                    acc[m][nb] = __builtin_amdgcn_mfma_f32_32x32x16_bf16(
                        a[m], bb[nb], acc[m][nb], 0, 0, 0);
        }
        __builtin_amdgcn_s_setprio(0);
        __builtin_amdgcn_s_barrier();   // reads done before buf[cur] reuse

        cur = (cur + 1 >= NSTAGE) ? 0 : cur + 1;
    }
    #undef STAGE

    // Epilogue: bias + exact GELU + W2 dot; reduce over f (rows).
    const float* b1e = b1 + e * HFD;
    const float* W2e = W2 + e * HFD;
    const float kInvSqrt2 = 0.70710678118654752f;

    float po0 = 0.f, po1 = 0.f;
    #pragma unroll
    for (int m = 0; m < 4; ++m) {
        const int base = fr * 128 + m * 32 + 4 * hi;
        #pragma unroll
        for (int r = 0; r < 16; ++r) {
            const int frow = base + (r & 3) + 8 * (r >> 2);
            const float bv = b1e[frow];
            const float wv = W2e[frow];
            const float h0 = acc[m][0][r] + bv;
            const float h1 = acc[m][1][r] + bv;
            po0 += 0.5f * h0 * (1.f + erff(h0 * kInvSqrt2)) * wv;
            po1 += 0.5f * h1 * (1.f + erff(h1 * kInvSqrt2)) * wv;
        }
    }
    po0 += __shfl_xor(po0, 32, 64);
    po1 += __shfl_xor(po1, 32, 64);

    if (hi == 0) {
        o_part[fr][tg * 64 + lo5]      = po0;
        o_part[fr][tg * 64 + 32 + lo5] = po1;
    }
    __syncthreads();

    if (tid < nt) {
        const int entry = bucket[e * B_TOK + start + tid];
        const float o = o_part[0][tid] + o_part[1][tid]
                      + o_part[2][tid] + o_part[3][tid];
        atomicAdd(&out_scores[entry >> 1], wslot[entry] * o);
    }
}

// ---------------------------------------------------------------------------
extern "C" void kernel_launch(void* const* d_in, const int* in_sizes, int n_in,
                              void* d_out, int out_size, void* d_ws, size_t ws_size,
                              hipStream_t stream)
{
    const float* x  = (const float*)d_in[0];   // [B, H]
    const float* W1 = (const float*)d_in[1];   // [E, H, HF]
    const float* b1 = (const float*)d_in[2];   // [E, HF]
    const float* W2 = (const float*)d_in[3];   // [E, HF]
    const float* Wg = (const float*)d_in[4];   // [H, E]
    const float* bg = (const float*)d_in[5];   // [E]

    float* out        = (float*)d_out;
    float* out_scores = out;                   // [B, 1]
    float* out_logits = out + B_TOK;           // [B, E]

    char* ws = (char*)d_ws;
    int*            counts = (int*)           (ws + OFF_COUNTS);
    int*            bucket = (int*)           (ws + OFF_BUCKET);
    float*          wslot  = (float*)         (ws + OFF_WSLOT);
    int*            route  = (int*)           (ws + OFF_ROUTE);
    float*          WgT    = (float*)         (ws + OFF_WGT);
    unsigned short* W1ts   = (unsigned short*)(ws + OFF_W1TS);
    unsigned short* xb     = (unsigned short*)(ws + OFF_XB);

    hipMemsetAsync(counts, 0, NE * sizeof(int), stream);
    hipMemsetAsync(out_scores, 0, B_TOK * sizeof(float), stream);

    wg_transpose_kernel<<<1, 256, 0, stream>>>(Wg, WgT);

    prep_w1_kernel<<<NE * NKSTEP, 256, 0, stream>>>(W1, W1ts);

    gate_logits_kernel<<<B_TOK / 4, 256, 0, stream>>>(x, WgT, bg, out_logits,
                                                      wslot, route, xb);

    route_kernel<<<B_TOK / 1024, 1024, 0, stream>>>(route, counts, bucket);

    expert_mfma_kernel<<<NE * (B_TOK / TM), 512, 0, stream>>>(
        xb, W1ts, b1, W2, counts, bucket, wslot, out_scores);
}